// Round 6
// baseline (199.087 us; speedup 1.0000x reference)
//
#include <hip/hip_runtime.h>

// MultiAdapterLinear: out = x @ W^T + b + 2.0 * (B[t] @ (A[t] @ x)) per-row task t
// Strategy: bucket rows by task; pre-gather x into bucket order as bf16;
// fused 256x128 bf16-MFMA GEMM, one chunk per WG, double-buffered LDS with
// COUNTED-vmcnt pipeline (T3+T4): stage(t+1) issued each iter, s_waitcnt
// vmcnt(6) waits only for stage(t) -- next-tile loads stay in flight across
// the barriers. A[t] hoisted fully into LDS (uniform 6 loads/thread/K-step).
// XCD task pinning; direct acc stores (no ostage -- it regressed R4).

#define D_IN   1024
#define D_OUTV 1024
#define NTASK  32
#define NROWS  32768
#define RLORA  16
#define SCALE  2.0f

typedef unsigned short u16;
typedef __attribute__((ext_vector_type(4))) unsigned short u16x4;
typedef __attribute__((ext_vector_type(8))) unsigned short u16x8;
typedef __attribute__((ext_vector_type(8))) short s16x8;
typedef __attribute__((ext_vector_type(4))) float f32x4;

// workspace layout (bytes)
#define WB_OFF   (0)
#define AB_OFF   (2*1024*1024)
#define BB_OFF   (3*1024*1024)
#define CNT_OFF  (4*1024*1024)
#define RIDX_OFF (CNT_OFF + 512)
#define XG_OFF   (8ull*1024*1024)

__device__ __forceinline__ u16 f2bf(float f) {
  union { float f; unsigned u; } v; v.f = f;
  unsigned r = v.u + 0x7fffu + ((v.u >> 16) & 1u);
  return (u16)(r >> 16);
}

__device__ __forceinline__ void gl2lds16(const void* g, void* s) {
  __builtin_amdgcn_global_load_lds(
      (const __attribute__((address_space(1))) unsigned*)g,
      (__attribute__((address_space(3))) unsigned*)s, 16, 0, 0);
}

__global__ void k_convert(const float* __restrict__ W, const float* __restrict__ A,
                          const float* __restrict__ B, u16* __restrict__ Wb,
                          u16* __restrict__ Ab, u16* __restrict__ Bb) {
  int g = blockIdx.x * blockDim.x + threadIdx.x;
  const int NW = D_OUTV * D_IN / 4;
  const int NA = NTASK * RLORA * D_IN / 4;
  const float* src; u16* dst; int idx;
  if (g < NW) { src = W; dst = Wb; idx = g; }
  else if (g < NW + NA) { src = A; dst = Ab; idx = g - NW; }
  else { src = B; dst = Bb; idx = g - NW - NA; }
  f32x4 v = *(const f32x4*)(src + (size_t)idx * 4);
  u16x4 o;
  o[0] = f2bf(v[0]); o[1] = f2bf(v[1]); o[2] = f2bf(v[2]); o[3] = f2bf(v[3]);
  *(u16x4*)(dst + (size_t)idx * 4) = o;
}

__global__ void k_hist(const int* __restrict__ tasks, int* __restrict__ cnt) {
  __shared__ int h[NTASK];
  int tid = threadIdx.x;
  if (tid < NTASK) h[tid] = 0;
  __syncthreads();
  atomicAdd(&h[tasks[blockIdx.x * 256 + tid]], 1);
  __syncthreads();
  if (tid < NTASK) atomicAdd(&cnt[tid], h[tid]);
}

__global__ void k_scan(int* __restrict__ cnt) {
  int t = threadIdx.x;
  int c = (t < NTASK) ? cnt[t] : 0;
  int v = c;
  for (int d = 1; d < NTASK; d <<= 1) {
    int u = __shfl_up(v, d, 64);
    if (t >= d) v += u;
  }
  if (t < NTASK) {
    int ex = v - c;
    cnt[64 + t] = ex;
    cnt[32 + t] = ex;
    if (t == NTASK - 1) cnt[64 + NTASK] = v;
  }
}

__global__ void k_scatter(const int* __restrict__ tasks, int* __restrict__ cnt,
                          int* __restrict__ ridx) {
  __shared__ int h[NTASK], basev[NTASK];
  int tid = threadIdx.x;
  int b = blockIdx.x * 256 + tid;
  int t = tasks[b];
  if (tid < NTASK) h[tid] = 0;
  __syncthreads();
  atomicAdd(&h[t], 1);
  __syncthreads();
  if (tid < NTASK) {
    basev[tid] = atomicAdd(&cnt[32 + tid], h[tid]);
    h[tid] = 0;
  }
  __syncthreads();
  int r = atomicAdd(&h[t], 1);
  ridx[basev[t] + r] = b;
}

__global__ void k_gatherx(const float* __restrict__ x, const int* __restrict__ ridx,
                          u16* __restrict__ xg) {
  int g = blockIdx.x * 256 + threadIdx.x;
  int pos = g >> 7;
  int c8  = (g & 127) << 3;
  int src = ridx[pos];
  f32x4 a = *(const f32x4*)(x + (size_t)src * D_IN + c8);
  f32x4 b = *(const f32x4*)(x + (size_t)src * D_IN + c8 + 4);
  u16x8 o;
  o[0] = f2bf(a[0]); o[1] = f2bf(a[1]); o[2] = f2bf(a[2]); o[3] = f2bf(a[3]);
  o[4] = f2bf(b[0]); o[5] = f2bf(b[1]); o[6] = f2bf(b[2]); o[7] = f2bf(b[3]);
  *(u16x8*)(xg + (size_t)pos * D_IN + c8) = o;
}

// ---------------- main fused GEMM ----------------
#define BM 256
#define BN 128
#define BK 64
#define NTHR 512
#define SLOTS 5
#define NWG (8 * NTASK * SLOTS)   // 1280; flat&7 == task&7 (XCD pin)

#define XSZ  (BM * BK)        // 16384 u16 per x buffer
#define WSZ  (BN * BK)        // 8192
#define ALSZ (RLORA * D_IN)   // 16384 (full-K A[t], staged once)
#define NKS  (D_IN / BK)      // 16 K-steps

__global__ __launch_bounds__(NTHR, 2) void k_main_c(
    const u16* __restrict__ xg, const float* __restrict__ bias,
    const u16* __restrict__ Wb, const u16* __restrict__ Ab, const u16* __restrict__ Bb,
    const int* __restrict__ cnt, const int* __restrict__ ridx,
    float* __restrict__ out) {
  __shared__ __align__(16) u16 xs[2 * XSZ];    // 64 KB
  __shared__ __align__(16) u16 wls[2 * WSZ];   // 32 KB
  __shared__ __align__(16) u16 als[ALSZ];      // 32 KB  (A[t], full K)
  __shared__ u16 bls[BN * 32];                 // 8 KB
  __shared__ u16 axs[BM * 32];                 // 16 KB
  __shared__ int rowid_l[BM];                  // 1 KB   -> 153 KB total

  const int tid = threadIdx.x;
  const int l   = tid & 63;
  const int w   = tid >> 6;          // 0..7
  const int wr  = w >> 1;            // 0..3 : 64-row slice of 256
  const int wc  = w & 1;             // 0..1 : 64-col slice of 128
  const int l15 = l & 15;
  const int lg  = l >> 4;

  // XCD-aware decode: flat%8 == task%8
  const int flat = blockIdx.x;
  const int idx  = flat >> 3;                 // 0..159
  const int task = (flat & 7) + ((idx & 3) << 3);
  const int rem  = idx >> 2;                  // 0..39
  const int cb   = rem & 7;                   // colblock 0..7
  const int slot = rem >> 3;                  // 0..4

  const int o0    = cnt[64 + task];
  const int count = cnt[64 + task + 1] - o0;
  const int base  = slot * BM;
  if (base >= count) return;                  // uniform exit, before any barrier

  // stage one (x,W) K-tile: exactly 6 global_load_lds per thread (uniform)
  auto stage = [&](int t, int bsel) {
    const int kk = t * BK;
    u16* xbuf = xs + bsel * XSZ;
    u16* wbuf = wls + bsel * WSZ;
#pragma unroll
    for (int i = 0; i < 4; i++) {
      int ch = i * NTHR + tid;                // 0..2047
      int r = ch >> 3, c = ch & 7;
      int gr = o0 + base + r;
      if (gr > NROWS - 1) gr = NROWS - 1;     // tail clamp (masked at store)
      gl2lds16(xg + (size_t)gr * D_IN + kk + ((c ^ (r & 7)) << 3), xbuf + ch * 8);
    }
#pragma unroll
    for (int i = 0; i < 2; i++) {
      int ch = i * NTHR + tid;                // 0..1023
      int wrow = ch >> 3, c = ch & 7;
      gl2lds16(Wb + (size_t)(cb * BN + wrow) * D_IN + kk + ((c ^ (wrow & 7)) << 3),
               wbuf + ch * 8);
    }
  };

  // ---- prologue: all vmcnt-contaminating work first, then ONE full drain ----
  for (int s = tid; s < BN * 4; s += NTHR) {  // bls (global reads -> LDS writes)
    int c = s >> 2, part = s & 3;
    u16x8 v = {0, 0, 0, 0, 0, 0, 0, 0};
    if (part < 2)
      v = *(const u16x8*)(Bb + ((size_t)(task * D_OUTV) + cb * BN + c) * RLORA + part * 8);
    *(u16x8*)&bls[c * 32 + ((part * 8) ^ ((c & 3) << 3))] = v;
  }
  for (int i = tid; i < BM * 32 / 8; i += NTHR) {
    u16x8 z = {0, 0, 0, 0, 0, 0, 0, 0};
    *(u16x8*)&axs[i * 8] = z;
  }
  if (tid < BM) {
    int s = base + tid;
    rowid_l[tid] = (s < count) ? ridx[o0 + s] : 0;
  }
  __syncthreads();   // full drain: vmcnt uniform 0 across all waves from here

  // A[t] full-K stage (4 loads) + tile-0 stage (6 loads): 10 in flight
#pragma unroll
  for (int i = 0; i < 4; i++) {
    int ch = i * NTHR + tid;                  // 0..2047
    int r = ch >> 7, c = ch & 127;            // r: 0..15, c: 16B chunk in row
    gl2lds16(Ab + (size_t)(task * RLORA + r) * D_IN + ((c ^ (r & 7)) << 3),
             als + ch * 8);
  }
  stage(0, 0);

  f32x4 acc[4][4];
  f32x4 axc[4];
  const f32x4 z4 = {0.f, 0.f, 0.f, 0.f};
#pragma unroll
  for (int m = 0; m < 4; m++) {
    axc[m] = z4;
#pragma unroll
    for (int n = 0; n < 4; n++) acc[m][n] = z4;
  }

  // ---- main loop: counted-vmcnt 2-deep pipeline ----
#pragma unroll 2
  for (int t = 0; t < NKS; ++t) {
    // B1: all waves finished previous iteration's ds_reads -> safe to overwrite
    asm volatile("" ::: "memory");
    __builtin_amdgcn_s_barrier();
    asm volatile("" ::: "memory");
    if (t < NKS - 1) stage(t + 1, (t + 1) & 1);   // 6 more in flight
    // wait only for stage(t) (and, at t==0, the A-stage): leave stage(t+1) in flight
    if (t < NKS - 1) {
      asm volatile("s_waitcnt vmcnt(6)" ::: "memory");
    } else {
      asm volatile("s_waitcnt vmcnt(0)" ::: "memory");
    }
    // B2: all waves' stage(t) data visible
    __builtin_amdgcn_s_barrier();
    __builtin_amdgcn_sched_barrier(0);

    const u16* xbuf = xs + (t & 1) * XSZ;
    const u16* wbuf = wls + (t & 1) * WSZ;
#pragma unroll
    for (int k0 = 0; k0 < BK; k0 += 32) {
      int kf = k0 + lg * 8;
      s16x8 xf[4], wf[4];
#pragma unroll
      for (int m = 0; m < 4; m++) {
        int row = wr * 64 + m * 16 + l15;
        xf[m] = *(const s16x8*)&xbuf[row * BK + (kf ^ ((row & 7) << 3))];
      }
#pragma unroll
      for (int n = 0; n < 4; n++) {
        int col = wc * 64 + n * 16 + l15;
        wf[n] = *(const s16x8*)&wbuf[col * BK + (kf ^ ((col & 7) << 3))];
      }
#pragma unroll
      for (int m = 0; m < 4; m++)
#pragma unroll
        for (int n = 0; n < 4; n++)
          acc[m][n] = __builtin_amdgcn_mfma_f32_16x16x32_bf16(xf[m], wf[n], acc[m][n], 0, 0, 0);
      if (wc == 0) {  // ax = x @ A[t]^T on col-wave-0 waves (A from full-K als)
        int kg = t * BK + kf;
        s16x8 af = *(const s16x8*)&als[l15 * D_IN + (kg ^ ((l15 & 7) << 3))];
#pragma unroll
        for (int m = 0; m < 4; m++)
          axc[m] = __builtin_amdgcn_mfma_f32_16x16x32_bf16(xf[m], af, axc[m], 0, 0, 0);
      }
    }
  }
  __syncthreads();

  // write scaled ax to LDS (bf16, swizzled; pad region untouched zeros)
  if (wc == 0) {
#pragma unroll
    for (int m = 0; m < 4; m++) {
#pragma unroll
      for (int j = 0; j < 4; j++) {
        int row = wr * 64 + m * 16 + lg * 4 + j;
        axs[row * 32 + (l15 ^ ((row & 3) << 3))] = f2bf(axc[m][j] * SCALE);
      }
    }
  }
  __syncthreads();

  // lora via one K=32 (zero-padded) MFMA per fragment, + bias, direct stores
  int kf2 = lg * 8;
  s16x8 axf[4], blf[4];
#pragma unroll
  for (int m = 0; m < 4; m++) {
    int row = wr * 64 + m * 16 + l15;
    axf[m] = *(const s16x8*)&axs[row * 32 + (kf2 ^ ((row & 3) << 3))];
  }
#pragma unroll
  for (int n = 0; n < 4; n++) {
    int col = wc * 64 + n * 16 + l15;
    blf[n] = *(const s16x8*)&bls[col * 32 + (kf2 ^ ((col & 3) << 3))];
  }
  float bv[4];
#pragma unroll
  for (int n = 0; n < 4; n++) bv[n] = bias[cb * BN + wc * 64 + n * 16 + l15];
#pragma unroll
  for (int n = 0; n < 4; n++) {
    int colg = cb * BN + wc * 64 + n * 16 + l15;
#pragma unroll
    for (int m = 0; m < 4; m++) {
      f32x4 r = __builtin_amdgcn_mfma_f32_16x16x32_bf16(axf[m], blf[n], acc[m][n], 0, 0, 0);
#pragma unroll
      for (int j = 0; j < 4; j++) {
        int lrow = wr * 64 + m * 16 + lg * 4 + j;
        if (base + lrow < count) {
          int grow = rowid_l[lrow];
          out[(size_t)grow * D_OUTV + colg] = r[j] + bv[n];
        }
      }
    }
  }
}

extern "C" void kernel_launch(void* const* d_in, const int* in_sizes, int n_in,
                              void* d_out, int out_size, void* d_ws, size_t ws_size,
                              hipStream_t stream) {
  const float* x     = (const float*)d_in[0];
  const int*   tasks = (const int*)d_in[1];
  const float* W     = (const float*)d_in[2];
  const float* bias  = (const float*)d_in[3];
  const float* A     = (const float*)d_in[4];
  const float* B     = (const float*)d_in[5];
  float* out = (float*)d_out;
  char* ws = (char*)d_ws;
  u16* Wb = (u16*)(ws + WB_OFF);
  u16* Ab = (u16*)(ws + AB_OFF);
  u16* Bb = (u16*)(ws + BB_OFF);
  int* cnt  = (int*)(ws + CNT_OFF);
  int* ridx = (int*)(ws + RIDX_OFF);
  u16* xg   = (u16*)(ws + XG_OFF);

  hipMemsetAsync(cnt, 0, 512, stream);
  k_convert<<<2048, 256, 0, stream>>>(W, A, B, Wb, Ab, Bb);
  k_hist<<<NROWS / 256, 256, 0, stream>>>(tasks, cnt);
  k_scan<<<1, 64, 0, stream>>>(cnt);
  k_scatter<<<NROWS / 256, 256, 0, stream>>>(tasks, cnt, ridx);
  k_gatherx<<<NROWS * D_IN / 8 / 256, 256, 0, stream>>>(x, ridx, xg);
  k_main_c<<<NWG, NTHR, 0, stream>>>(xg, bias, Wb, Ab, Bb, cnt, ridx, out);
}

// Round 7
// 183.880 us; speedup vs baseline: 1.0827x; 1.0827x over previous
//
#include <hip/hip_runtime.h>

// MultiAdapterLinear: out = x @ W^T + b + 2.0 * (B[t] @ (A[t] @ x)) per-row task t
// Strategy: bucket rows by task; pre-gather x into bucket order as bf16;
// fused 256x128 bf16-MFMA GEMM, one chunk per WG, double-buffered LDS,
// XCD task pinning with L2-FOOTPRINT-AWARE ordering: the 8 WGs adjacent on
// an XCD are the 8 colblocks of one (task,slot) -> they share one 512KB xg
// chunk and exactly cover the 2MB W; resident set/XCD ~= 4MB = L2 size.
// LoRA fused in-loop; LDS-staged full-cacheline output stores.

#define D_IN   1024
#define D_OUTV 1024
#define NTASK  32
#define NROWS  32768
#define RLORA  16
#define SCALE  2.0f

typedef unsigned short u16;
typedef __attribute__((ext_vector_type(4))) unsigned short u16x4;
typedef __attribute__((ext_vector_type(8))) unsigned short u16x8;
typedef __attribute__((ext_vector_type(8))) short s16x8;
typedef __attribute__((ext_vector_type(4))) float f32x4;

// workspace layout (bytes)
#define WB_OFF   (0)
#define AB_OFF   (2*1024*1024)
#define BB_OFF   (3*1024*1024)
#define CNT_OFF  (4*1024*1024)
#define RIDX_OFF (CNT_OFF + 512)
#define XG_OFF   (8ull*1024*1024)

__device__ __forceinline__ u16 f2bf(float f) {
  union { float f; unsigned u; } v; v.f = f;
  unsigned r = v.u + 0x7fffu + ((v.u >> 16) & 1u);
  return (u16)(r >> 16);
}

__device__ __forceinline__ void gl2lds16(const void* g, void* s) {
  __builtin_amdgcn_global_load_lds(
      (const __attribute__((address_space(1))) unsigned*)g,
      (__attribute__((address_space(3))) unsigned*)s, 16, 0, 0);
}

__global__ void k_convert(const float* __restrict__ W, const float* __restrict__ A,
                          const float* __restrict__ B, u16* __restrict__ Wb,
                          u16* __restrict__ Ab, u16* __restrict__ Bb) {
  int g = blockIdx.x * blockDim.x + threadIdx.x;
  const int NW = D_OUTV * D_IN / 4;
  const int NA = NTASK * RLORA * D_IN / 4;
  const float* src; u16* dst; int idx;
  if (g < NW) { src = W; dst = Wb; idx = g; }
  else if (g < NW + NA) { src = A; dst = Ab; idx = g - NW; }
  else { src = B; dst = Bb; idx = g - NW - NA; }
  f32x4 v = *(const f32x4*)(src + (size_t)idx * 4);
  u16x4 o;
  o[0] = f2bf(v[0]); o[1] = f2bf(v[1]); o[2] = f2bf(v[2]); o[3] = f2bf(v[3]);
  *(u16x4*)(dst + (size_t)idx * 4) = o;
}

__global__ void k_hist(const int* __restrict__ tasks, int* __restrict__ cnt) {
  __shared__ int h[NTASK];
  int tid = threadIdx.x;
  if (tid < NTASK) h[tid] = 0;
  __syncthreads();
  atomicAdd(&h[tasks[blockIdx.x * 256 + tid]], 1);
  __syncthreads();
  if (tid < NTASK) atomicAdd(&cnt[tid], h[tid]);
}

__global__ void k_scan(int* __restrict__ cnt) {
  int t = threadIdx.x;
  int c = (t < NTASK) ? cnt[t] : 0;
  int v = c;
  for (int d = 1; d < NTASK; d <<= 1) {
    int u = __shfl_up(v, d, 64);
    if (t >= d) v += u;
  }
  if (t < NTASK) {
    int ex = v - c;
    cnt[64 + t] = ex;
    cnt[32 + t] = ex;
    if (t == NTASK - 1) cnt[64 + NTASK] = v;
  }
}

__global__ void k_scatter(const int* __restrict__ tasks, int* __restrict__ cnt,
                          int* __restrict__ ridx) {
  __shared__ int h[NTASK], basev[NTASK];
  int tid = threadIdx.x;
  int b = blockIdx.x * 256 + tid;
  int t = tasks[b];
  if (tid < NTASK) h[tid] = 0;
  __syncthreads();
  atomicAdd(&h[t], 1);
  __syncthreads();
  if (tid < NTASK) {
    basev[tid] = atomicAdd(&cnt[32 + tid], h[tid]);
    h[tid] = 0;
  }
  __syncthreads();
  int r = atomicAdd(&h[t], 1);
  ridx[basev[t] + r] = b;
}

__global__ void k_gatherx(const float* __restrict__ x, const int* __restrict__ ridx,
                          u16* __restrict__ xg) {
  int g = blockIdx.x * 256 + threadIdx.x;
  int pos = g >> 7;
  int c8  = (g & 127) << 3;
  int src = ridx[pos];
  f32x4 a = *(const f32x4*)(x + (size_t)src * D_IN + c8);
  f32x4 b = *(const f32x4*)(x + (size_t)src * D_IN + c8 + 4);
  u16x8 o;
  o[0] = f2bf(a[0]); o[1] = f2bf(a[1]); o[2] = f2bf(a[2]); o[3] = f2bf(a[3]);
  o[4] = f2bf(b[0]); o[5] = f2bf(b[1]); o[6] = f2bf(b[2]); o[7] = f2bf(b[3]);
  *(u16x8*)(xg + (size_t)pos * D_IN + c8) = o;
}

// ---------------- main fused GEMM ----------------
#define BM 256
#define BN 128
#define BK 64
#define NTHR 512
#define SLOTS 5
#define NWG (8 * NTASK * SLOTS)   // 1280

#define XSZ (BM * BK)      // u16 per x buffer (16384)
#define WSZ (BN * BK)      // 8192
#define ASZ (RLORA * BK)   // 1024

__global__ __launch_bounds__(NTHR, 2) void k_main_c(
    const u16* __restrict__ xg, const float* __restrict__ bias,
    const u16* __restrict__ Wb, const u16* __restrict__ Ab, const u16* __restrict__ Bb,
    const int* __restrict__ cnt, const int* __restrict__ ridx,
    float* __restrict__ out) {
  // [xs dbuf 64K][wls dbuf 32K][als dbuf 4K] ; ostage(64K f32) aliases xs dbuf
  __shared__ __align__(16) u16 smem[2 * XSZ + 2 * WSZ + 2 * ASZ];
  __shared__ u16 bls[BN * 32];       // B[t] slice (rank padded 16->32)
  __shared__ u16 axs[BM * 32];       // ax (rank padded, zero pad region)
  __shared__ int rowid_l[BM];
  u16* xs  = smem;
  u16* wls = smem + 2 * XSZ;
  u16* als = wls + 2 * WSZ;
  float* ostage = (float*)smem;      // 128 rows x 128 cols f32 = 64 KB

  const int tid = threadIdx.x;
  const int l   = tid & 63;
  const int w   = tid >> 6;          // 0..7
  const int wr  = w >> 1;            // 0..3 : 64-row slice
  const int wc  = w & 1;             // 0..1 : 64-col slice
  const int l15 = l & 15;
  const int lg  = l >> 4;

  // L2-footprint-aware decode: flat&7 = XCD; cb INNERMOST so the 8 adjacent
  // WGs on an XCD are the 8 colblocks of one (task,slot): they share one
  // 512KB xg chunk and exactly cover the 2MB W -> ~4MB resident per XCD.
  const int flat = blockIdx.x;
  const int xcd  = flat & 7;
  const int j    = flat >> 3;                 // 0..159
  const int cb   = j & 7;                     // colblock 0..7 (inner)
  const int g    = j >> 3;                    // 0..19
  const int task = xcd + 8 * (g & 3);
  const int slot = g >> 2;                    // 0..4

  const int o0    = cnt[64 + task];
  const int count = cnt[64 + task + 1] - o0;
  const int base  = slot * BM;
  if (base >= count) return;                  // uniform exit, no barriers yet

  auto stage = [&](int t, int bsel) {
    const int kk = t * BK;
    u16* xbuf = xs + bsel * XSZ;
    u16* wbuf = wls + bsel * WSZ;
    u16* abuf = als + bsel * ASZ;
#pragma unroll
    for (int i = 0; i < 4; i++) {
      int ch = i * NTHR + tid;                // 0..2047
      int r = ch >> 3, c = ch & 7;
      int gr = o0 + base + r;
      if (gr > NROWS - 1) gr = NROWS - 1;     // tail clamp (masked at store)
      gl2lds16(xg + (size_t)gr * D_IN + kk + ((c ^ (r & 7)) << 3), xbuf + ch * 8);
    }
#pragma unroll
    for (int i = 0; i < 2; i++) {
      int ch = i * NTHR + tid;                // 0..1023
      int wrow = ch >> 3, c = ch & 7;
      gl2lds16(Wb + (size_t)(cb * BN + wrow) * D_IN + kk + ((c ^ (wrow & 7)) << 3),
               wbuf + ch * 8);
    }
    if (tid < 128) {
      int r = tid >> 3, c = tid & 7;
      gl2lds16(Ab + (size_t)(task * RLORA + r) * D_IN + kk + ((c ^ (r & 7)) << 3),
               abuf + tid * 8);
    }
  };

  f32x4 acc[4][4];
  f32x4 axc[4];
  const f32x4 z4 = {0.f, 0.f, 0.f, 0.f};
#pragma unroll
  for (int m = 0; m < 4; m++) {
    axc[m] = z4;
#pragma unroll
    for (int n = 0; n < 4; n++) acc[m][n] = z4;
  }

  // prologue: issue tile-0 loads first, then small LDS inits, one barrier
  stage(0, 0);
  for (int s = tid; s < BN * 4; s += NTHR) {  // bls: 512 8-elem chunks
    int c = s >> 2, part = s & 3;
    u16x8 v = {0, 0, 0, 0, 0, 0, 0, 0};
    if (part < 2)
      v = *(const u16x8*)(Bb + ((size_t)(task * D_OUTV) + cb * BN + c) * RLORA + part * 8);
    *(u16x8*)&bls[c * 32 + ((part * 8) ^ ((c & 3) << 3))] = v;
  }
  for (int i = tid; i < BM * 32 / 8; i += NTHR) {
    u16x8 z = {0, 0, 0, 0, 0, 0, 0, 0};
    *(u16x8*)&axs[i * 8] = z;
  }
  if (tid < BM) {
    int s = base + tid;
    rowid_l[tid] = (s < count) ? ridx[o0 + s] : 0;
  }
  __syncthreads();

  // main loop: stage(t+1) issued BEFORE compute(t); single barrier per K-step.
#pragma unroll 2
  for (int t = 0; t < D_IN / BK; ++t) {
    if (t < D_IN / BK - 1) stage(t + 1, (t + 1) & 1);
    const u16* xbuf = xs + (t & 1) * XSZ;
    const u16* wbuf = wls + (t & 1) * WSZ;
    const u16* abuf = als + (t & 1) * ASZ;
#pragma unroll
    for (int k0 = 0; k0 < BK; k0 += 32) {
      int kf = k0 + lg * 8;
      s16x8 xf[4], wf[4];
#pragma unroll
      for (int m = 0; m < 4; m++) {
        int row = wr * 64 + m * 16 + l15;
        xf[m] = *(const s16x8*)&xbuf[row * BK + (kf ^ ((row & 7) << 3))];
      }
#pragma unroll
      for (int n = 0; n < 4; n++) {
        int col = wc * 64 + n * 16 + l15;
        wf[n] = *(const s16x8*)&wbuf[col * BK + (kf ^ ((col & 7) << 3))];
      }
#pragma unroll
      for (int m = 0; m < 4; m++)
#pragma unroll
        for (int n = 0; n < 4; n++)
          acc[m][n] = __builtin_amdgcn_mfma_f32_16x16x32_bf16(xf[m], wf[n], acc[m][n], 0, 0, 0);
      if (wc == 0) {  // ax = x @ A[t]^T on col-wave-0 waves
        s16x8 af = *(const s16x8*)&abuf[l15 * BK + (kf ^ ((l15 & 7) << 3))];
#pragma unroll
        for (int m = 0; m < 4; m++)
          axc[m] = __builtin_amdgcn_mfma_f32_16x16x32_bf16(xf[m], af, axc[m], 0, 0, 0);
      }
    }
    __syncthreads();
  }

  // write scaled ax to LDS (bf16, swizzled; pad region untouched zeros)
  if (wc == 0) {
#pragma unroll
    for (int m = 0; m < 4; m++) {
#pragma unroll
      for (int j2 = 0; j2 < 4; j2++) {
        int row = wr * 64 + m * 16 + lg * 4 + j2;
        axs[row * 32 + (l15 ^ ((row & 3) << 3))] = f2bf(axc[m][j2] * SCALE);
      }
    }
  }
  __syncthreads();

  // lora via one K=32 (zero-padded) MFMA per fragment, + bias, into acc
  int kf2 = lg * 8;
  s16x8 axf[4], blf[4];
#pragma unroll
  for (int m = 0; m < 4; m++) {
    int row = wr * 64 + m * 16 + l15;
    axf[m] = *(const s16x8*)&axs[row * 32 + (kf2 ^ ((row & 3) << 3))];
  }
#pragma unroll
  for (int n = 0; n < 4; n++) {
    int col = wc * 64 + n * 16 + l15;
    blf[n] = *(const s16x8*)&bls[col * 32 + (kf2 ^ ((col & 3) << 3))];
  }
  float bv[4];
#pragma unroll
  for (int n = 0; n < 4; n++) bv[n] = bias[cb * BN + wc * 64 + n * 16 + l15];
#pragma unroll
  for (int n = 0; n < 4; n++)
#pragma unroll
    for (int m = 0; m < 4; m++) {
      acc[m][n] = __builtin_amdgcn_mfma_f32_16x16x32_bf16(axf[m], blf[n], acc[m][n], 0, 0, 0);
#pragma unroll
      for (int j2 = 0; j2 < 4; j2++) acc[m][n][j2] += bv[n];
    }

  // LDS-staged full-cacheline stores: two 128-row halves through ostage
#pragma unroll
  for (int half = 0; half < 2; ++half) {
    __syncthreads();
    if ((wr >> 1) == half) {
#pragma unroll
      for (int m = 0; m < 4; m++)
#pragma unroll
        for (int n = 0; n < 4; n++)
#pragma unroll
          for (int j2 = 0; j2 < 4; j2++) {
            int rl  = (wr & 1) * 64 + m * 16 + lg * 4 + j2;  // 0..127
            int col = wc * 64 + n * 16 + l15;
            ostage[rl * 128 + (col ^ (((rl >> 2) & 3) << 3))] = acc[m][n][j2];
          }
    }
    __syncthreads();
#pragma unroll
    for (int it = 0; it < 8; ++it) {
      int ch = it * NTHR + tid;        // 0..4095 chunks of 16B
      int rl = ch >> 5;                // 0..127
      int cq = ch & 31;
      int lrow = half * 128 + rl;
      if (base + lrow < count) {
        int grow = rowid_l[lrow];
        f32x4 v = *(const f32x4*)&ostage[rl * 128 + ((cq * 4) ^ (((rl >> 2) & 3) << 3))];
        *(f32x4*)&out[(size_t)grow * D_OUTV + cb * BN + cq * 4] = v;
      }
    }
  }
}

extern "C" void kernel_launch(void* const* d_in, const int* in_sizes, int n_in,
                              void* d_out, int out_size, void* d_ws, size_t ws_size,
                              hipStream_t stream) {
  const float* x     = (const float*)d_in[0];
  const int*   tasks = (const int*)d_in[1];
  const float* W     = (const float*)d_in[2];
  const float* bias  = (const float*)d_in[3];
  const float* A     = (const float*)d_in[4];
  const float* B     = (const float*)d_in[5];
  float* out = (float*)d_out;
  char* ws = (char*)d_ws;
  u16* Wb = (u16*)(ws + WB_OFF);
  u16* Ab = (u16*)(ws + AB_OFF);
  u16* Bb = (u16*)(ws + BB_OFF);
  int* cnt  = (int*)(ws + CNT_OFF);
  int* ridx = (int*)(ws + RIDX_OFF);
  u16* xg   = (u16*)(ws + XG_OFF);

  hipMemsetAsync(cnt, 0, 512, stream);
  k_convert<<<2048, 256, 0, stream>>>(W, A, B, Wb, Ab, Bb);
  k_hist<<<NROWS / 256, 256, 0, stream>>>(tasks, cnt);
  k_scan<<<1, 64, 0, stream>>>(cnt);
  k_scatter<<<NROWS / 256, 256, 0, stream>>>(tasks, cnt, ridx);
  k_gatherx<<<NROWS * D_IN / 8 / 256, 256, 0, stream>>>(x, ridx, xg);
  k_main_c<<<NWG, NTHR, 0, stream>>>(xg, bias, Wb, Ab, Bb, cnt, ridx, out);
}

// Round 8
// 169.549 us; speedup vs baseline: 1.1742x; 1.0845x over previous
//
#include <hip/hip_runtime.h>

// MultiAdapterLinear: out = x @ W^T + b + 2.0 * (B[t] @ (A[t] @ x)) per-row task t
// Strategy: bucket rows by task; pre-gather x into bucket order as bf16;
// fused 128x128 bf16-MFMA GEMM (R2 structure: 256 thr, 51.7KB LDS -> 3 WG/CU
// for cross-WG latency hiding, multi-chunk WGs, direct stores) with R7's
// L2-footprint-aware decode (8 adjacent WGs on an XCD = 8 colblocks of one
// (task,slot) -> ~3MB resident per XCD L2). LoRA fused in-loop.

#define D_IN   1024
#define D_OUTV 1024
#define NTASK  32
#define NROWS  32768
#define RLORA  16
#define SCALE  2.0f

typedef unsigned short u16;
typedef __attribute__((ext_vector_type(4))) unsigned short u16x4;
typedef __attribute__((ext_vector_type(8))) unsigned short u16x8;
typedef __attribute__((ext_vector_type(8))) short s16x8;
typedef __attribute__((ext_vector_type(4))) float f32x4;

// workspace layout (bytes)
#define WB_OFF   (0)
#define AB_OFF   (2*1024*1024)
#define BB_OFF   (3*1024*1024)
#define CNT_OFF  (4*1024*1024)
#define RIDX_OFF (CNT_OFF + 512)
#define XG_OFF   (8ull*1024*1024)

__device__ __forceinline__ u16 f2bf(float f) {
  union { float f; unsigned u; } v; v.f = f;
  unsigned r = v.u + 0x7fffu + ((v.u >> 16) & 1u);
  return (u16)(r >> 16);
}

__device__ __forceinline__ void gl2lds16(const void* g, void* s) {
  __builtin_amdgcn_global_load_lds(
      (const __attribute__((address_space(1))) unsigned*)g,
      (__attribute__((address_space(3))) unsigned*)s, 16, 0, 0);
}

__global__ void k_convert(const float* __restrict__ W, const float* __restrict__ A,
                          const float* __restrict__ B, u16* __restrict__ Wb,
                          u16* __restrict__ Ab, u16* __restrict__ Bb) {
  int g = blockIdx.x * blockDim.x + threadIdx.x;
  const int NW = D_OUTV * D_IN / 4;
  const int NA = NTASK * RLORA * D_IN / 4;
  const float* src; u16* dst; int idx;
  if (g < NW) { src = W; dst = Wb; idx = g; }
  else if (g < NW + NA) { src = A; dst = Ab; idx = g - NW; }
  else { src = B; dst = Bb; idx = g - NW - NA; }
  f32x4 v = *(const f32x4*)(src + (size_t)idx * 4);
  u16x4 o;
  o[0] = f2bf(v[0]); o[1] = f2bf(v[1]); o[2] = f2bf(v[2]); o[3] = f2bf(v[3]);
  *(u16x4*)(dst + (size_t)idx * 4) = o;
}

__global__ void k_hist(const int* __restrict__ tasks, int* __restrict__ cnt) {
  __shared__ int h[NTASK];
  int tid = threadIdx.x;
  if (tid < NTASK) h[tid] = 0;
  __syncthreads();
  atomicAdd(&h[tasks[blockIdx.x * 256 + tid]], 1);
  __syncthreads();
  if (tid < NTASK) atomicAdd(&cnt[tid], h[tid]);
}

__global__ void k_scan(int* __restrict__ cnt) {
  int t = threadIdx.x;
  int c = (t < NTASK) ? cnt[t] : 0;
  int v = c;
  for (int d = 1; d < NTASK; d <<= 1) {
    int u = __shfl_up(v, d, 64);
    if (t >= d) v += u;
  }
  if (t < NTASK) {
    int ex = v - c;
    cnt[64 + t] = ex;
    cnt[32 + t] = ex;
    if (t == NTASK - 1) cnt[64 + NTASK] = v;
  }
}

__global__ void k_scatter(const int* __restrict__ tasks, int* __restrict__ cnt,
                          int* __restrict__ ridx) {
  __shared__ int h[NTASK], basev[NTASK];
  int tid = threadIdx.x;
  int b = blockIdx.x * 256 + tid;
  int t = tasks[b];
  if (tid < NTASK) h[tid] = 0;
  __syncthreads();
  atomicAdd(&h[t], 1);
  __syncthreads();
  if (tid < NTASK) {
    basev[tid] = atomicAdd(&cnt[32 + tid], h[tid]);
    h[tid] = 0;
  }
  __syncthreads();
  int r = atomicAdd(&h[t], 1);
  ridx[basev[t] + r] = b;
}

__global__ void k_gatherx(const float* __restrict__ x, const int* __restrict__ ridx,
                          u16* __restrict__ xg) {
  int g = blockIdx.x * 256 + threadIdx.x;
  int pos = g >> 7;
  int c8  = (g & 127) << 3;
  int src = ridx[pos];
  f32x4 a = *(const f32x4*)(x + (size_t)src * D_IN + c8);
  f32x4 b = *(const f32x4*)(x + (size_t)src * D_IN + c8 + 4);
  u16x8 o;
  o[0] = f2bf(a[0]); o[1] = f2bf(a[1]); o[2] = f2bf(a[2]); o[3] = f2bf(a[3]);
  o[4] = f2bf(b[0]); o[5] = f2bf(b[1]); o[6] = f2bf(b[2]); o[7] = f2bf(b[3]);
  *(u16x8*)(xg + (size_t)pos * D_IN + c8) = o;
}

// ---------------- main fused GEMM ----------------
#define BM 128
#define BN 128
#define BK 64
#define NTHR 256
#define SLOTS 3
#define NWG (8 * NTASK * SLOTS)   // 768 WGs = 3 per CU, one residency round

__global__ __launch_bounds__(NTHR, 3) void k_main_c(
    const u16* __restrict__ xg, const float* __restrict__ bias,
    const u16* __restrict__ Wb, const u16* __restrict__ Ab, const u16* __restrict__ Bb,
    const int* __restrict__ cnt, const int* __restrict__ ridx,
    float* __restrict__ out) {
  __shared__ __align__(16) u16 xs[BM * BK];    // 16 KB
  __shared__ __align__(16) u16 wls[BN * BK];   // 16 KB
  __shared__ u16 als[RLORA * BK];              // 2 KB
  __shared__ u16 axs[BM * 32];                 // 8 KB (rank padded 16->32)
  __shared__ u16 bls[BN * 32];                 // 8 KB (rank padded)
  __shared__ int rowid_l[BM];                  // 0.5 KB  -> ~50.5 KB total

  const int tid = threadIdx.x;
  const int l   = tid & 63;
  const int w   = tid >> 6;          // 0..3
  const int wr  = w >> 1;            // 0..1 : 64-row slice
  const int wc  = w & 1;             // 0..1 : 64-col slice
  const int l15 = l & 15;
  const int lg  = l >> 4;

  // L2-footprint-aware decode: flat&7 = XCD; cb innermost so the 8 adjacent
  // WGs on an XCD share one 256KB xg chunk and cover the whole 2MB W.
  const int flat = blockIdx.x;
  const int xcd  = flat & 7;
  const int j    = flat >> 3;                 // 0..95
  const int cb   = j & 7;                     // colblock 0..7 (inner)
  const int g    = j >> 3;                    // 0..11
  const int task = xcd + 8 * (g & 3);
  const int slot = g >> 2;                    // 0..2

  const int o0    = cnt[64 + task];
  const int count = cnt[64 + task + 1] - o0;

  // stage B[t] col-slice once, zero-padded to 32 on rank dim, swizzled
  for (int s = tid; s < 512; s += NTHR) {
    int c = s >> 2, part = s & 3;
    u16x8 v = {0, 0, 0, 0, 0, 0, 0, 0};
    if (part < 2)
      v = *(const u16x8*)(Bb + ((size_t)(task * D_OUTV) + cb * BN + c) * RLORA + part * 8);
    *(u16x8*)&bls[c * 32 + ((part * 8) ^ ((c & 3) << 3))] = v;
  }
  // zero axs fully once (pad slots stay zero; real slots rewritten per chunk)
  for (int i = tid; i < BM * 32 / 8; i += NTHR) {
    u16x8 z = {0, 0, 0, 0, 0, 0, 0, 0};
    *(u16x8*)&axs[i * 8] = z;
  }

  for (int chunk = slot; chunk * BM < count; chunk += SLOTS) {
    const int base = chunk * BM;
    __syncthreads();  // protect rowid_l/axs from previous chunk's readers
    if (tid < BM) {
      int s = base + tid;
      rowid_l[tid] = (s < count) ? ridx[o0 + s] : 0;
    }

    f32x4 acc[4][4];
    f32x4 axc[4];
    const f32x4 z4 = {0.f, 0.f, 0.f, 0.f};
#pragma unroll
    for (int m = 0; m < 4; m++) {
      axc[m] = z4;
#pragma unroll
      for (int n = 0; n < 4; n++) acc[m][n] = z4;
    }

    for (int kk = 0; kk < D_IN; kk += BK) {
      __syncthreads();  // previous compute done before overwriting tiles
      // x tile: contiguous bucketed bf16 rows; source chunk pre-swizzled
#pragma unroll
      for (int i = 0; i < 4; i++) {
        int ch = i * NTHR + tid;          // 0..1023
        int r = ch >> 3, c = ch & 7;
        int gr = o0 + base + r;
        if (gr > NROWS - 1) gr = NROWS - 1;   // tail clamp (masked at store)
        gl2lds16(xg + (size_t)gr * D_IN + kk + ((c ^ (r & 7)) << 3), &xs[ch * 8]);
      }
      // W tile
#pragma unroll
      for (int i = 0; i < 4; i++) {
        int ch = i * NTHR + tid;
        int wrow = ch >> 3, c = ch & 7;
        gl2lds16(Wb + (size_t)(cb * BN + wrow) * D_IN + kk + ((c ^ (wrow & 7)) << 3),
                 &wls[ch * 8]);
      }
      // A[t] tile
      if (tid < 128) {
        int r = tid >> 3, c = tid & 7;
        gl2lds16(Ab + (size_t)(task * RLORA + r) * D_IN + kk + ((c ^ (r & 7)) << 3),
                 &als[tid * 8]);
      }
      __syncthreads();  // drains vmcnt (global_load_lds) + lgkm

#pragma unroll
      for (int k0 = 0; k0 < BK; k0 += 32) {
        int kf = k0 + lg * 8;
        s16x8 xf[4], wf[4];
#pragma unroll
        for (int m = 0; m < 4; m++) {
          int row = wr * 64 + m * 16 + l15;
          xf[m] = *(const s16x8*)&xs[row * BK + (kf ^ ((row & 7) << 3))];
        }
#pragma unroll
        for (int n = 0; n < 4; n++) {
          int col = wc * 64 + n * 16 + l15;
          wf[n] = *(const s16x8*)&wls[col * BK + (kf ^ ((col & 7) << 3))];
        }
#pragma unroll
        for (int m = 0; m < 4; m++)
#pragma unroll
          for (int n = 0; n < 4; n++)
            acc[m][n] = __builtin_amdgcn_mfma_f32_16x16x32_bf16(xf[m], wf[n], acc[m][n], 0, 0, 0);
        if (wc == 0) {  // ax = x @ A[t]^T on col-wave-0 waves
          s16x8 af = *(const s16x8*)&als[l15 * BK + (kf ^ ((l15 & 7) << 3))];
#pragma unroll
          for (int m = 0; m < 4; m++)
            axc[m] = __builtin_amdgcn_mfma_f32_16x16x32_bf16(xf[m], af, axc[m], 0, 0, 0);
        }
      }
    }
    __syncthreads();  // all compute done

    // write scaled ax to LDS (bf16, swizzled; pad region untouched zeros)
    if (wc == 0) {
#pragma unroll
      for (int m = 0; m < 4; m++) {
#pragma unroll
        for (int j2 = 0; j2 < 4; j2++) {
          int row = wr * 64 + m * 16 + lg * 4 + j2;
          axs[row * 32 + (l15 ^ ((row & 3) << 3))] = f2bf(axc[m][j2] * SCALE);
        }
      }
    }
    __syncthreads();

    // lora via one K=32 (zero-padded) MFMA per fragment, + bias, direct stores
    int kf2 = lg * 8;
    s16x8 axf[4], blf[4];
#pragma unroll
    for (int m = 0; m < 4; m++) {
      int row = wr * 64 + m * 16 + l15;
      axf[m] = *(const s16x8*)&axs[row * 32 + (kf2 ^ ((row & 3) << 3))];
    }
#pragma unroll
    for (int n = 0; n < 4; n++) {
      int col = wc * 64 + n * 16 + l15;
      blf[n] = *(const s16x8*)&bls[col * 32 + (kf2 ^ ((col & 3) << 3))];
    }
#pragma unroll
    for (int n = 0; n < 4; n++) {
      int colg = cb * BN + wc * 64 + n * 16 + l15;
      float bv = bias[colg];
#pragma unroll
      for (int m = 0; m < 4; m++) {
        f32x4 r = __builtin_amdgcn_mfma_f32_16x16x32_bf16(axf[m], blf[n], acc[m][n], 0, 0, 0);
#pragma unroll
        for (int j2 = 0; j2 < 4; j2++) {
          int lrow = wr * 64 + m * 16 + lg * 4 + j2;
          if (base + lrow < count) {
            int grow = rowid_l[lrow];
            out[(size_t)grow * D_OUTV + colg] = r[j2] + bv;
          }
        }
      }
    }
  }
}

extern "C" void kernel_launch(void* const* d_in, const int* in_sizes, int n_in,
                              void* d_out, int out_size, void* d_ws, size_t ws_size,
                              hipStream_t stream) {
  const float* x     = (const float*)d_in[0];
  const int*   tasks = (const int*)d_in[1];
  const float* W     = (const float*)d_in[2];
  const float* bias  = (const float*)d_in[3];
  const float* A     = (const float*)d_in[4];
  const float* B     = (const float*)d_in[5];
  float* out = (float*)d_out;
  char* ws = (char*)d_ws;
  u16* Wb = (u16*)(ws + WB_OFF);
  u16* Ab = (u16*)(ws + AB_OFF);
  u16* Bb = (u16*)(ws + BB_OFF);
  int* cnt  = (int*)(ws + CNT_OFF);
  int* ridx = (int*)(ws + RIDX_OFF);
  u16* xg   = (u16*)(ws + XG_OFF);

  hipMemsetAsync(cnt, 0, 512, stream);
  k_convert<<<2048, 256, 0, stream>>>(W, A, B, Wb, Ab, Bb);
  k_hist<<<NROWS / 256, 256, 0, stream>>>(tasks, cnt);
  k_scan<<<1, 64, 0, stream>>>(cnt);
  k_scatter<<<NROWS / 256, 256, 0, stream>>>(tasks, cnt, ridx);
  k_gatherx<<<NROWS * D_IN / 8 / 256, 256, 0, stream>>>(x, ridx, xg);
  k_main_c<<<NWG, NTHR, 0, stream>>>(xg, bias, Wb, Ab, Bb, cnt, ridx, out);
}